// Round 2
// baseline (19476.674 us; speedup 1.0000x reference)
//
#include <hip/hip_runtime.h>
#include <hip/hip_cooperative_groups.h>

namespace cg = cooperative_groups;

typedef unsigned short u16;
typedef unsigned int u32;
typedef __attribute__((ext_vector_type(4))) float f32x4;
typedef __attribute__((ext_vector_type(8))) short s16x8;

#define B_ 64
#define T_ 512
#define E_ 1024
#define H_ 1024
#define N4_ 4096   // 4*H

__device__ __forceinline__ u16 f32_bf16(float f) {
  union { float f; u32 u; } v; v.f = f;
  u32 r = v.u + 0x7FFFu + ((v.u >> 16) & 1u);
  return (u16)(r >> 16);
}
__device__ __forceinline__ float bf16_f32(u16 h) {
  union { u32 u; float f; } v; v.u = ((u32)h) << 16;
  return v.f;
}
__device__ __forceinline__ void async16(void* lds, const void* g) {
  __builtin_amdgcn_global_load_lds(
      (const __attribute__((address_space(1))) void*)g,
      (__attribute__((address_space(3))) void*)lds, 16, 0, 0);
}
__device__ __forceinline__ float sigmoidf_(float x) {
  return 1.0f / (1.0f + __expf(-x));
}

// ---------------- fp32 -> bf16 bulk convert (4 elems/thread) ----------------
__global__ __launch_bounds__(256) void cvt4(const float* __restrict__ s,
                                            u16* __restrict__ d, int n4) {
  int i = blockIdx.x * 256 + threadIdx.x;
  if (i < n4) {
    float4 v = ((const float4*)s)[i];
    ushort4 o;
    o.x = f32_bf16(v.x); o.y = f32_bf16(v.y);
    o.z = f32_bf16(v.z); o.w = f32_bf16(v.w);
    ((ushort4*)d)[i] = o;
  }
}

// ---------------- init: a0->bf16, bias concat ----------------
__global__ __launch_bounds__(256) void init_k(const float* __restrict__ a0,
                                              const float* __restrict__ bc,
                                              const float* __restrict__ bu,
                                              const float* __restrict__ bf_,
                                              const float* __restrict__ bo,
                                              u16* __restrict__ abuf0,
                                              float* __restrict__ bias4) {
  int i = blockIdx.x * 256 + threadIdx.x;   // 65536 threads
  abuf0[i] = f32_bf16(a0[i]);
  if (i < N4_) {
    int g = i >> 10, h = i & 1023;
    const float* bp = (g == 0) ? bc : (g == 1) ? bu : (g == 2) ? bf_ : bo;
    bias4[i] = bp[h];
  }
}

// ---------------- phase 1: P[t][b][n] = bf16( X @ WxT + bias ) ----------------
__global__ __launch_bounds__(256) void gemm_p1(const u16* __restrict__ Xbf,
                                               const u16* __restrict__ Wbf,
                                               const float* __restrict__ bias4,
                                               u16* __restrict__ P) {
  __shared__ __align__(16) u16 As[128 * 64];
  __shared__ __align__(16) u16 Bs[128 * 64];
  int tid = threadIdx.x;
  int wid = tid >> 6, lane = tid & 63;
  int lane15 = lane & 15, quad = lane >> 4;
  int m0 = blockIdx.y * 128, n0 = blockIdx.x * 128;
  int wm = (wid >> 1) * 64, wn = (wid & 1) * 64;

  f32x4 acc[4][4] = {};

  for (int kc = 0; kc < 1024; kc += 64) {
    __syncthreads();
    for (int i = 0; i < 8; ++i) {
      int c = wid * 8 + i;
      int o = c * 1024 + lane * 16;
      int e = (o & 16383) >> 1;
      int row = e >> 6, kcol = e & 63;
      if (o < 16384) {
        async16((char*)As + c * 1024,
                Xbf + (size_t)(m0 + row) * 1024 + kc + kcol);
      } else {
        async16((char*)Bs + (c - 16) * 1024,
                Wbf + (size_t)(n0 + row) * 2048 + 1024 + kc + kcol);
      }
    }
    __syncthreads();
    for (int s = 0; s < 2; ++s) {
      s16x8 bfrag[4], afrag[4];
      for (int ni = 0; ni < 4; ++ni)
        bfrag[ni] = *(const s16x8*)&Bs[(wn + ni * 16 + lane15) * 64 + s * 32 + quad * 8];
      for (int mi = 0; mi < 4; ++mi)
        afrag[mi] = *(const s16x8*)&As[(wm + mi * 16 + lane15) * 64 + s * 32 + quad * 8];
      for (int mi = 0; mi < 4; ++mi)
        for (int ni = 0; ni < 4; ++ni)
          acc[mi][ni] = __builtin_amdgcn_mfma_f32_16x16x32_bf16(
              afrag[mi], bfrag[ni], acc[mi][ni], 0, 0, 0);
    }
  }
  for (int mi = 0; mi < 4; ++mi) {
    int mbase = m0 + wm + mi * 16 + quad * 4;
    for (int ni = 0; ni < 4; ++ni) {
      int n = n0 + wn + ni * 16 + lane15;
      float bv = bias4[n];
      for (int r = 0; r < 4; ++r) {
        int m = mbase + r;
        int b = m >> 9, t = m & 511;
        float v = acc[mi][ni][r] + bv;
        P[(size_t)(t * 64 + b) * N4_ + n] = f32_bf16(v);
      }
    }
  }
}

// ---------------- phase 2: persistent cooperative scan ----------------
// 256 WGs; WG i owns h in [4i,4i+4) for all 4 gates (N-tile of 16 cols).
// Resident B-slice in LDS (fragment order); K=1024 split over 4 waves;
// c state in registers; one grid.sync per step.
__global__ __launch_bounds__(256) void scan_k(const u16* __restrict__ Wbf,
                                              const u16* __restrict__ P,
                                              u16* __restrict__ ab0,
                                              u16* __restrict__ ab1,
                                              const float* __restrict__ c0,
                                              float* __restrict__ a_out,
                                              float* __restrict__ out_aT,
                                              float* __restrict__ out_cT) {
  cg::grid_group grid = cg::this_grid();
  __shared__ __align__(16) u16 Bsf[32 * 64 * 8];        // 32 KB, fragment-ordered
  __shared__ __align__(16) float scratch[4 * 64 * 17];  // 17.4 KB, padded stride
  __shared__ __align__(16) u16 Pl[64 * 16];             // 2 KB

  int tid = threadIdx.x;
  int w = tid >> 6, lane = tid & 63;
  int lane15 = lane & 15, quad = lane >> 4;
  int h0 = blockIdx.x * 4;

  // Load resident B tile once, pre-swizzled to fragment order:
  // value B[col=l&15][k=ks*32+(l>>4)*8+j] at flat chunk (ks*64+l)*8+j.
  for (int i = 0; i < 8; ++i) {
    int q = i * 256 + tid;               // [0,2048)
    int ks = q >> 6, l = q & 63;
    int c = l & 15, qd = l >> 4;
    int g = c >> 2, hh = c & 3;
    *(s16x8*)&Bsf[q * 8] =
        *(const s16x8*)(Wbf + (size_t)(g * 1024 + h0 + hh) * 2048 + ks * 32 + qd * 8);
  }
  // c state in registers: thread owns (b = tid>>2, h = h0 + (tid&3))
  int eb = tid >> 2, ehh = tid & 3;
  float creg = c0[eb * 1024 + h0 + ehh];
  __syncthreads();

  for (int t = 0; t < T_; ++t) {
    const u16* ap = (t & 1) ? ab1 : ab0;
    u16* an = (t & 1) ? ab0 : ab1;
    // P prefetch (needed only at epilogue): thread (pb=tid>>2, pg=tid&3)
    int pb = tid >> 2, pg = tid & 3;
    ushort4 pv = *(const ushort4*)(P + (size_t)(t * 64 + pb) * N4_ + pg * 1024 + h0);

    f32x4 acc[4] = {};
    for (int ks = 0; ks < 8; ++ks) {
      int kb = w * 256 + ks * 32;
      s16x8 bfrag = *(const s16x8*)&Bsf[((w * 8 + ks) * 64 + lane) * 8];
      for (int mi = 0; mi < 4; ++mi) {
        s16x8 afrag =
            *(const s16x8*)(ap + (size_t)(mi * 16 + lane15) * 1024 + kb + quad * 8);
        acc[mi] = __builtin_amdgcn_mfma_f32_16x16x32_bf16(afrag, bfrag, acc[mi], 0, 0, 0);
      }
    }
    // partial sums -> LDS (per-wave region, no cross-wave WAW)
    for (int mi = 0; mi < 4; ++mi)
      for (int r = 0; r < 4; ++r)
        scratch[w * 1088 + (mi * 16 + quad * 4 + r) * 17 + lane15] = acc[mi][r];
    *(ushort4*)&Pl[pb * 16 + pg * 4] = pv;
    __syncthreads();
    // epilogue: thread (eb, ehh); reduce 4 waves, add P(+bias), gates, state
    float R[4];
    for (int g = 0; g < 4; ++g) {
      float s = 0.0f;
      for (int ww = 0; ww < 4; ++ww)
        s += scratch[ww * 1088 + eb * 17 + g * 4 + ehh];
      R[g] = s + bf16_f32(Pl[eb * 16 + g * 4 + ehh]);
    }
    float cand = tanhf(R[0]);
    float gu = sigmoidf_(R[1]);
    float gf = sigmoidf_(R[2]);
    float go = sigmoidf_(R[3]);
    creg = gu * cand + gf * creg;
    float a1 = go * tanhf(creg);
    a_out[((size_t)eb * T_ + t) * H_ + h0 + ehh] = a1;
    an[eb * 1024 + h0 + ehh] = f32_bf16(a1);
    if (t == T_ - 1) {
      out_aT[eb * 1024 + h0 + ehh] = a1;
      out_cT[eb * 1024 + h0 + ehh] = creg;
    }
    grid.sync();
  }
}

extern "C" void kernel_launch(void* const* d_in, const int* in_sizes, int n_in,
                              void* d_out, int out_size, void* d_ws, size_t ws_size,
                              hipStream_t stream) {
  const float* x_i = (const float*)d_in[0];
  const float* a0  = (const float*)d_in[1];
  const float* c0  = (const float*)d_in[2];
  const float* w[4] = {(const float*)d_in[3], (const float*)d_in[4],
                       (const float*)d_in[5], (const float*)d_in[6]};
  const float* bb[4] = {(const float*)d_in[7], (const float*)d_in[8],
                        (const float*)d_in[9], (const float*)d_in[10]};
  float* out = (float*)d_out;

  char* ws = (char*)d_ws;
  u16* Wbf   = (u16*)ws;                          // 16,777,216 B
  u16* Xbf   = (u16*)(ws + 16777216);             // 67,108,864 B
  u16* P     = (u16*)(ws + 83886080);             // 268,435,456 B
  float* bias4 = (float*)(ws + 352321536);        // 16,384 B
  u16* abuf0 = (u16*)(ws + 352337920);            // 131,072 B
  u16* abuf1 = (u16*)(ws + 352468992);            // 131,072 B

  for (int g = 0; g < 4; ++g)
    cvt4<<<2048, 256, 0, stream>>>(w[g], Wbf + (size_t)g * 1024 * 2048, 524288);
  cvt4<<<32768, 256, 0, stream>>>(x_i, Xbf, 8388608);
  init_k<<<256, 256, 0, stream>>>(a0, bb[0], bb[1], bb[2], bb[3], abuf0, bias4);
  gemm_p1<<<dim3(32, 256), 256, 0, stream>>>(Xbf, Wbf, bias4, P);

  float* out_aT = out + 33554432;
  float* out_cT = out + 33619968;
  void* args[] = {(void*)&Wbf, (void*)&P, (void*)&abuf0, (void*)&abuf1,
                  (void*)&c0, (void*)&out, (void*)&out_aT, (void*)&out_cT};
  hipLaunchCooperativeKernel((void*)scan_k, dim3(256), dim3(256), args, 0, stream);
}